// Round 2
// baseline (172.228 us; speedup 1.0000x reference)
//
#include <hip/hip_runtime.h>
#include <hip/hip_bf16.h>

#define NN 128
#define DD 128

typedef __attribute__((ext_vector_type(8))) short bf16x8;
typedef __attribute__((ext_vector_type(4))) float floatx4;
typedef __attribute__((ext_vector_type(2))) float floatx2;

__device__ __forceinline__ unsigned short f2bf(float f) {
    // round-to-nearest-even bf16 (finite inputs only)
    unsigned int bits = __float_as_uint(f);
    unsigned int r = bits + 0x7FFFu + ((bits >> 16) & 1u);
    return (unsigned short)(r >> 16);
}

__device__ __forceinline__ unsigned short f2bf_hw(float f) {
    unsigned int r;
    asm("v_cvt_pk_bf16_f32 %0, %1, %2" : "=v"(r) : "v"(f), "v"(f));
    return (unsigned short)r;
}

__device__ __forceinline__ unsigned int f2bf_pk(float lo, float hi) {
    unsigned int r;
    asm("v_cvt_pk_bf16_f32 %0, %1, %2" : "=v"(r) : "v"(lo), "v"(hi));
    return r;
}

// ws layout (float units)
#define WS_HJB0 0        // 8*128*128 bf16 = 65536 f   (Hjb exchange ping)
#define WS_HJB1 65536    // (pong)
#define WS_W1T  131072   // 34816 ushorts: w1t[n][d] = W1[n&127][(n>>7)*128+d], stride 136
#define WS_W2B  148480   // 17408 ushorts: w2b[e][d] = W2[e][d], stride 136
#define WS_TABA 157184   // 14*128 f32:  hja table per token value
#define WS_TABB 158976   // 14*128 bf16: Hjb(+b1) table per token value (896 f)
#define WS_CNT  159872   // 8 batches x 4 rounds x 32 ints

// ---------------- K_init: weight images + per-token GEMM1 tables + counters ----------------
__global__ __launch_bounds__(256) void k_init(const int* __restrict__ tok,
                                              const float* __restrict__ embf,
                                              const float* __restrict__ W1f,
                                              const float* __restrict__ b1f,
                                              const float* __restrict__ W2f,
                                              float* __restrict__ ws) {
    unsigned short* gw1t = (unsigned short*)(ws + WS_W1T);
    unsigned short* gw2b = (unsigned short*)(ws + WS_W2B);
    float* taba = ws + WS_TABA;
    unsigned int* tabb32 = (unsigned int*)(ws + WS_TABB);
    int* cnt = (int*)(ws + WS_CNT);
    int blk = blockIdx.x, t = threadIdx.x;

    if (blk == 0) {
        // per-token-value GEMM1 tables, via the SAME MFMA sequence k_main uses (bit-identical)
        __shared__ __align__(16) unsigned short wt[256 * 136];
        __shared__ __align__(16) unsigned short et_[16 * 136];
        __shared__ float b1s[128];
        for (int idx = t; idx < 256 * 136; idx += 256) {
            int e = idx / 136, d = idx - e * 136;
            wt[idx] = (d < 128) ? f2bf(W1f[(e & 127) * 256 + (e >> 7) * 128 + d])
                                : (unsigned short)0;
        }
        for (int i = t; i < 16 * 136; i += 256) et_[i] = 0;
        if (t < 128) b1s[t] = b1f[t];
        __syncthreads();
        if (t < 224) {                    // rows 0..13 = bf16(embed[v])
            int v = t >> 4, d0 = (t & 15) * 8;
#pragma unroll
            for (int k2 = 0; k2 < 8; ++k2) et_[v * 136 + d0 + k2] = f2bf(embf[v * 128 + d0 + k2]);
        }
        __syncthreads();
        int wv = t >> 6, lane = t & 63, col = lane & 15, quad = lane >> 4;
        bf16x8 af[4];
#pragma unroll
        for (int ks = 0; ks < 4; ++ks)
            af[ks] = *reinterpret_cast<const bf16x8*>(&et_[col * 136 + ks * 32 + quad * 8]);
#pragma unroll
        for (int c = 0; c < 4; ++c) {
            int nt = wv * 4 + c;
            floatx4 acc = (floatx4){0.f, 0.f, 0.f, 0.f};
#pragma unroll
            for (int ks = 0; ks < 4; ++ks)
                acc = __builtin_amdgcn_mfma_f32_16x16x32_bf16(af[ks],
                        *reinterpret_cast<const bf16x8*>(&wt[(nt * 16 + col) * 136 + ks * 32 + quad * 8]),
                        acc, 0, 0, 0);
            if (nt < 8) {
#pragma unroll
                for (int rr = 0; rr < 4; ++rr) {
                    int v = quad * 4 + rr;
                    if (v < 14) taba[v * 128 + nt * 16 + col] = acc[rr];
                }
            } else {
                int d = (nt - 8) * 16 + col;
                float bv = b1s[d];
#pragma unroll
                for (int rr = 0; rr < 4; ++rr) {
                    float val = acc[rr] + bv;
                    float po = __shfl_xor(val, 1, 64);
                    int v = quad * 4 + rr;
                    if (!(col & 1) && v < 14)
                        tabb32[v * 64 + (d >> 1)] =
                            (unsigned int)f2bf(val) | ((unsigned int)f2bf(po) << 16);
                }
            }
        }
    } else if (blk < 10) {                // gw1t (256x136)
        int base = (blk - 1) * 4096;
#pragma unroll
        for (int it = 0; it < 16; ++it) {
            int idx = base + it * 256 + t;
            if (idx < 256 * 136) {
                int e = idx / 136, d = idx - e * 136;
                gw1t[idx] = (d < 128) ? f2bf(W1f[(e & 127) * 256 + (e >> 7) * 128 + d])
                                      : (unsigned short)0;
            }
        }
    } else if (blk < 15) {                // gw2b (128x136)
        int base = (blk - 10) * 4096;
#pragma unroll
        for (int it = 0; it < 16; ++it) {
            int idx = base + it * 256 + t;
            if (idx < 128 * 136) {
                int e = idx / 136, d = idx - e * 136;
                gw2b[idx] = (d < 128) ? f2bf(W2f[e * 128 + d]) : (unsigned short)0;
            }
        }
    } else {                              // zero barrier counters
#pragma unroll
        for (int it = 0; it < 4; ++it) cnt[it * 256 + t] = 0;
    }
}

// ---------------- K_main: 5 rounds + head. 256 blocks x 512 threads, 1 block/CU ------------
__global__ __launch_bounds__(512, 2) void k_main(const int* __restrict__ tokp,
                                                 const float* __restrict__ embf,
                                                 const float* __restrict__ Af,
                                                 const float* __restrict__ b1f,
                                                 const float* __restrict__ b2f,
                                                 const float* __restrict__ Wo1f,
                                                 const float* __restrict__ bo1f,
                                                 const float* __restrict__ Wo2f,
                                                 float* __restrict__ ws,
                                                 float* __restrict__ outp) {
    __shared__ __align__(16) unsigned short w1t[256 * 136];   // 69632 B (head reuses as Wo1 f32)
    __shared__ __align__(16) unsigned short w2b[128 * 136];   // 34816 B
    __shared__ __align__(16) unsigned short xo[4 * 136];      // own 4 x-rows, bf16
    __shared__ __align__(16) float red[4][4][128];            // 8192 B (head reuses as rs)
    __shared__ __align__(16) float zs[4][128];                // 2048 B
    __shared__ float a_s[4][128];                             // 2048 B
    __shared__ __align__(16) float hja_s[4][128];             // 2048 B   (total ~117 KB)

    const unsigned short* gw1t = (const unsigned short*)(ws + WS_W1T);
    const unsigned short* gw2b = (const unsigned short*)(ws + WS_W2B);
    const float* taba = ws + WS_TABA;
    const unsigned short* tabb16 = (const unsigned short*)(ws + WS_TABB);
    int* cnt = (int*)(ws + WS_CNT);

    int blk = blockIdx.x;
    // all 32 blocks of a batch share blk&7 -> same XCD (L2-local barrier + exchange)
    int b = blk & 7, g = blk >> 3, i0 = g * 4;
    int t = threadIdx.x;
    int wave = t >> 6, lane = t & 63;
    int col = lane & 15, quad = lane >> 4;

    // ---- persistent staging (once) ----
    {
        const uint4* s1 = (const uint4*)gw1t; uint4* d1 = (uint4*)w1t;
#pragma unroll
        for (int it = 0; it < 9; ++it) { int idx = it * 512 + t; if (idx < 4352) d1[idx] = s1[idx]; }
        const uint4* s2 = (const uint4*)gw2b; uint4* d2 = (uint4*)w2b;
#pragma unroll
        for (int it = 0; it < 5; ++it) { int idx = it * 512 + t; if (idx < 2176) d2[idx] = s2[idx]; }
    }
    int we = wave & 1, wj = wave >> 1;
    int ebase = we * 64, jbase = wj * 32;
    float b1r0 = 0.f, b1r1 = 0.f;
    if (wave >= 4) {                       // b1 for this wave's publish columns
        b1r0 = b1f[((wave - 4) * 2 + 0) * 16 + col];
        b1r1 = b1f[((wave - 4) * 2 + 1) * 16 + col];
    }
    float b2r[4];
#pragma unroll
    for (int et = 0; et < 4; ++et) b2r[et] = b2f[ebase + et * 16 + col];
    a_s[t >> 7][t & 127] = Af[(b * NN + (t & 127)) * NN + i0 + (t >> 7)];  // A[b, j, i0+ii]

    int ii_own = t >> 7, e_own = t & 127;
    int trow = tokp[b * NN + i0 + ii_own];
    float xown = embf[trow * DD + e_own];          // owned x element, carried in f32
    hja_s[ii_own][e_own] = taba[trow * 128 + e_own];   // round-0 hja from table
    __syncthreads();

    for (int r = 0; r < 5; ++r) {
        unsigned short* gbw = (unsigned short*)(ws + ((r & 1) ? WS_HJB1 : WS_HJB0));

        if (r > 0) {
            // ---- mini-GEMM1: own 4 rows only (A rows 0..3 = xo, rest zero) ----
            bf16x8 af[4];
#pragma unroll
            for (int ks = 0; ks < 4; ++ks) {
                bf16x8 z = {0, 0, 0, 0, 0, 0, 0, 0};
                af[ks] = (col < 4) ? *reinterpret_cast<const bf16x8*>(&xo[col * 136 + ks * 32 + quad * 8]) : z;
            }
            floatx4 acc[2];
            acc[0] = (floatx4){0.f, 0.f, 0.f, 0.f};
            acc[1] = (floatx4){0.f, 0.f, 0.f, 0.f};
#pragma unroll
            for (int u = 0; u < 2; ++u)
#pragma unroll
                for (int ks = 0; ks < 4; ++ks) {
                    int nt = wave * 2 + u;
                    acc[u] = __builtin_amdgcn_mfma_f32_16x16x32_bf16(af[ks],
                        *reinterpret_cast<const bf16x8*>(&w1t[(nt * 16 + col) * 136 + ks * 32 + quad * 8]),
                        acc[u], 0, 0, 0);
                }
            if (wave < 4) {                // hja for own rows (local)
                if (quad == 0) {
#pragma unroll
                    for (int u = 0; u < 2; ++u)
#pragma unroll
                        for (int rr = 0; rr < 4; ++rr)
                            hja_s[rr][(wave * 2 + u) * 16 + col] = acc[u][rr];
                }
            } else {                       // Hjb(+b1) own rows -> publish bf16
#pragma unroll
                for (int u = 0; u < 2; ++u) {
                    float bv = u ? b1r1 : b1r0;
                    int d = ((wave - 4) * 2 + u) * 16 + col;
#pragma unroll
                    for (int rr = 0; rr < 4; ++rr) {
                        float val = acc[u][rr] + bv;
                        float po = __shfl_xor(val, 1, 64);
                        if (quad == 0 && !(col & 1)) {
                            int row = b * NN + i0 + rr;
                            __hip_atomic_store((unsigned int*)gbw + row * 64 + (d >> 1),
                                               f2bf_pk(val, po),
                                               __ATOMIC_RELAXED, __HIP_MEMORY_SCOPE_AGENT);
                        }
                    }
                }
            }
            // ---- per-batch barrier: Hjb complete ----
            __atomic_signal_fence(__ATOMIC_SEQ_CST);
            __builtin_amdgcn_s_waitcnt(0);
            __syncthreads();
            if (t == 0) {
                int* myc = cnt + (b * 4 + (r - 1)) * 32;
                __hip_atomic_fetch_add(myc, 1, __ATOMIC_RELAXED, __HIP_MEMORY_SCOPE_AGENT);
                while (__hip_atomic_load(myc, __ATOMIC_RELAXED, __HIP_MEMORY_SCOPE_AGENT) < 32)
                    __builtin_amdgcn_s_sleep(1);
            }
            __syncthreads();
        }

        // ---- GEMM2: M = relu(hja_i + Hjb_j + .) @ W2^T; msg = sum_j a_j * M ----
        union U4 { bf16x8 v; unsigned int u[4]; };
        U4 L[2][4];
        {
            const unsigned short* base0;
            const unsigned short* base1;
            if (r == 0) {                  // round 0: gather rows from token table
                base0 = tabb16 + (size_t)tokp[b * NN + jbase + col] * 128;
                base1 = tabb16 + (size_t)tokp[b * NN + jbase + 16 + col] * 128;
            } else {
                base0 = gbw + (size_t)(b * NN + jbase + col) * 128;
                base1 = gbw + (size_t)(b * NN + jbase + 16 + col) * 128;
            }
            base0 += quad * 8; base1 += quad * 8;
            asm volatile(                  // 8x dwordx4: this wave's 32 Hjb j-rows
                "global_load_dwordx4 %0, %8, off sc0 sc1\n\t"
                "global_load_dwordx4 %1, %8, off offset:64 sc0 sc1\n\t"
                "global_load_dwordx4 %2, %8, off offset:128 sc0 sc1\n\t"
                "global_load_dwordx4 %3, %8, off offset:192 sc0 sc1\n\t"
                "global_load_dwordx4 %4, %9, off sc0 sc1\n\t"
                "global_load_dwordx4 %5, %9, off offset:64 sc0 sc1\n\t"
                "global_load_dwordx4 %6, %9, off offset:128 sc0 sc1\n\t"
                "global_load_dwordx4 %7, %9, off offset:192 sc0 sc1"
                : "=&v"(L[0][0].v), "=&v"(L[0][1].v), "=&v"(L[0][2].v), "=&v"(L[0][3].v),
                  "=&v"(L[1][0].v), "=&v"(L[1][1].v), "=&v"(L[1][2].v), "=&v"(L[1][3].v)
                : "v"(base0), "v"(base1)
                : "memory");
        }
        bf16x8 bw[4][4];                   // W2 fragments (LDS, hot) — overlaps load latency
#pragma unroll
        for (int et = 0; et < 4; ++et)
#pragma unroll
            for (int ks = 0; ks < 4; ++ks)
                bw[et][ks] = *reinterpret_cast<const bf16x8*>(&w2b[(ebase + et * 16 + col) * 136 + ks * 32 + quad * 8]);
        asm volatile("s_waitcnt vmcnt(0)" ::: "memory");
        __builtin_amdgcn_sched_barrier(0);

        floatx2 hjc[2][4][4];              // unpack Hjb once (reused by all 4 ii)
#pragma unroll
        for (int jt = 0; jt < 2; ++jt)
#pragma unroll
            for (int ks = 0; ks < 4; ++ks)
#pragma unroll
                for (int p = 0; p < 4; ++p) {
                    floatx2 h2;
                    h2.x = __uint_as_float(L[jt][ks].u[p] << 16);
                    h2.y = __uint_as_float(L[jt][ks].u[p] & 0xFFFF0000u);
                    hjc[jt][ks][p] = h2;
                }

#pragma unroll
        for (int ii = 0; ii < 4; ++ii) {
            floatx4 acc2[2][4];
#pragma unroll
            for (int jt = 0; jt < 2; ++jt)
#pragma unroll
                for (int et = 0; et < 4; ++et) acc2[jt][et] = (floatx4){0.f, 0.f, 0.f, 0.f};
#pragma unroll
            for (int ks = 0; ks < 4; ++ks) {
                int k0 = ks * 32 + quad * 8;
                floatx2 ha[4];
#pragma unroll
                for (int p = 0; p < 4; ++p)
                    ha[p] = *reinterpret_cast<const floatx2*>(&hja_s[ii][k0 + 2 * p]);
#pragma unroll
                for (int jt = 0; jt < 2; ++jt) {
                    U4 Ho;
#pragma unroll
                    for (int p = 0; p < 4; ++p) {   // H = relu(hja_i + Hjb): pk add + hw cvt
                        floatx2 s2;
                        asm("v_pk_add_f32 %0, %1, %2" : "=v"(s2) : "v"(hjc[jt][ks][p]), "v"(ha[p]));
                        float f0 = fmaxf(s2.x, 0.f);
                        float f1 = fmaxf(s2.y, 0.f);
                        Ho.u[p] = f2bf_pk(f0, f1);
                    }
#pragma unroll
                    for (int et = 0; et < 4; ++et)
                        acc2[jt][et] = __builtin_amdgcn_mfma_f32_16x16x32_bf16(Ho.v, bw[et][ks], acc2[jt][et], 0, 0, 0);
                }
            }
#pragma unroll
            for (int et = 0; et < 4; ++et) {
                float be = b2r[et];
                float s = 0.f;
#pragma unroll
                for (int jt = 0; jt < 2; ++jt) {
                    int j0 = jbase + jt * 16 + quad * 4;
#pragma unroll
                    for (int rr = 0; rr < 4; ++rr)
                        s += a_s[ii][j0 + rr] * fmaxf(acc2[jt][et][rr] + be, 0.f);
                }
                s += __shfl_xor(s, 16, 64);
                s += __shfl_xor(s, 32, 64);
                if (quad == 0) red[wj][ii][ebase + et * 16 + col] = s;
            }
        }
        __syncthreads();
        // ---- finalize: xown += msg; stash bf16 x for next round's mini-GEMM1 ----
        {
            float msg = red[0][ii_own][e_own] + red[1][ii_own][e_own]
                      + red[2][ii_own][e_own] + red[3][ii_own][e_own];
            xown += msg;
            if (r < 4) xo[ii_own * 136 + e_own] = f2bf_hw(xown);
            else       zs[ii_own][e_own] = xown;
        }
        if (r < 4) __syncthreads();
    }

    // ---- head (own 4 rows) ----
    float* wo1s = (float*)w1t;   // 128x136 f32 = 69632 B, exactly the w1t footprint
#pragma unroll
    for (int it = 0; it < 8; ++it) {
        int idx4 = it * 512 + t;                  // 4096 float4s
        int e = idx4 >> 5, d4 = idx4 & 31;
        float4 wv = reinterpret_cast<const float4*>(Wo1f)[idx4];
        *reinterpret_cast<float4*>(&wo1s[e * 136 + d4 * 4]) = wv;
    }
    __syncthreads();
    {
        int e = t & 127, ii = t >> 7;
        float acc = 0.f;
#pragma unroll
        for (int d4 = 0; d4 < 32; ++d4) {
            float4 w = *reinterpret_cast<const float4*>(&wo1s[e * 136 + d4 * 4]);
            float4 z = *reinterpret_cast<const float4*>(&zs[ii][d4 * 4]);
            acc += w.x * z.x + w.y * z.y + w.z * z.z + w.w * z.w;
        }
        ((float*)red)[ii * 128 + e] = fmaxf(acc + bo1f[e], 0.f);
    }
    __syncthreads();
    if (t < 40) {
        int ii = t / 10, o = t - ii * 10;
        const float* rsrow = (const float*)red + ii * 128;
        const float4* w2r = reinterpret_cast<const float4*>(Wo2f + o * DD);
        float s = 0.f;
#pragma unroll
        for (int e4 = 0; e4 < 32; ++e4) {
            float4 rv = *reinterpret_cast<const float4*>(&rsrow[e4 * 4]);
            float4 wv = w2r[e4];
            s += rv.x * wv.x + rv.y * wv.y + rv.z * wv.z + rv.w * wv.w;
        }
        int row = b * NN + i0 + ii;
        outp[80 + row * 10 + o] = s;             // x_all (8,128,10)
        if (i0 + ii == 0) outp[b * 10 + o] = s;  // out == x_all[:,0,:]
    }
}

extern "C" void kernel_launch(void* const* d_in, const int* in_sizes, int n_in,
                              void* d_out, int out_size, void* d_ws, size_t ws_size,
                              hipStream_t stream) {
    const int*   tok  = (const int*)d_in[0];
    const float* Af   = (const float*)d_in[1];
    const float* embf = (const float*)d_in[2];
    const float* W1f  = (const float*)d_in[3];
    const float* b1f  = (const float*)d_in[4];
    const float* W2f  = (const float*)d_in[5];
    const float* b2f  = (const float*)d_in[6];
    const float* Wo1f = (const float*)d_in[7];
    const float* bo1f = (const float*)d_in[8];
    const float* Wo2f = (const float*)d_in[9];

    float* ws  = (float*)d_ws;
    float* out = (float*)d_out;

    k_init<<<16, 256, 0, stream>>>(tok, embf, W1f, b1f, W2f, ws);
    k_main<<<256, 512, 0, stream>>>(tok, embf, Af, b1f, b2f, Wo1f, bo1f, Wo2f, ws, out);
}